// Round 12
// baseline (112.663 us; speedup 1.0000x reference)
//
#include <hip/hip_runtime.h>
#include <hip/hip_bf16.h>
#include <stdint.h>

#define T_TOK 8192
#define DIM   1024
#define NEXP  8
#define BM    128
#define BN    128
#define BK2   32

typedef __bf16 bf16_t;
typedef bf16_t bf16x8 __attribute__((ext_vector_type(8)));
typedef bf16_t bf16x4 __attribute__((ext_vector_type(4)));
typedef float  f32x4  __attribute__((ext_vector_type(4)));

// ---- workspace layout (bytes) ----
// cnt: 64 counters, EACH ON ITS OWN 64B CACHE LINE (atomic ping-pong fix, R6)
#define WS_CNT    0                  // 64 * 16 ints = 4 KB
#define CIDX(p)   ((p) << 4)
#define WS_LIST   8192               // 64 * 8192 ints = 2 MB
#define WS_XBF    (4u << 20)         // T*D bf16 = 16 MB
#define WS_W2     (20u << 20)        // WSUM 28*2MB = 56 MB (psum) or WT 16MB (fallback)
#define WS_NEED_PSUM ((size_t)76 << 20)

// pair index tables: pk -> (a,b), a<b
__device__ const int d_PA[28] = {0,0,0,0,0,0,0,1,1,1,1,1,1,2,2,2,2,2,3,3,3,3,4,4,4,5,5,6};
__device__ const int d_PB[28] = {1,2,3,4,5,6,7,2,3,4,5,6,7,3,4,5,6,7,4,5,6,7,5,6,7,6,7,7};

// async 16B global -> LDS (lds dest is wave-uniform base; HW adds lane*16)
__device__ __forceinline__ void gload16(const void* g, void* l) {
    __builtin_amdgcn_global_load_lds(
        (const __attribute__((address_space(1))) unsigned int*)g,
        (__attribute__((address_space(3))) unsigned int*)l, 16, 0, 0);
}

// BK2=32 tile: row = 64B = 4 chunks of 16B; chunk' = chunk ^ ((r>>1)&3)
// -> max 2-way bank aliasing on ds_read_b128 (free). k in elements.
__device__ __forceinline__ int swz32(int r, int k) {
    return ((r * BK2 + k) * 2) ^ (((r >> 1) & 3) << 4);
}

#define WAITCNT_VM0()   do { asm volatile("s_waitcnt vmcnt(0)" ::: "memory"); \
                             __builtin_amdgcn_sched_barrier(0); } while (0)
#define WAITCNT_VM4()   do { asm volatile("s_waitcnt vmcnt(4)" ::: "memory"); \
                             __builtin_amdgcn_sched_barrier(0); } while (0)
#define WAITCNT_LGKM0() do { asm volatile("s_waitcnt lgkmcnt(0)" ::: "memory"); \
                             __builtin_amdgcn_sched_barrier(0); } while (0)
#define BARRIER()       do { __builtin_amdgcn_s_barrier(); \
                             __builtin_amdgcn_sched_barrier(0); } while (0)

// ------------------------------------------------------------------
// zero_cnt: zero the 4 KB counter region (replaces hipMemsetAsync)
// ------------------------------------------------------------------
__global__ void zero_cnt(int4* cnt4) {
    cnt4[threadIdx.x] = int4{0, 0, 0, 0};   // 256 * 16 B = 4 KB
}

// ------------------------------------------------------------------
// fused_pre (R12): INTERLEAVED roles for overlap.
//   PSUM=1: grid 8192. bx%8==0 -> route (1024 blocks, 8 tokens each);
//           else -> R6-style direct pair-transpose (7168 blocks):
//           W2[pk][f][d] = bf16(ew[a][d][f] + ew[b][d][f]), 64x64 tile.
//           ew re-reads (7x) stream from L3 at ~13 TB/s - cheap (R6-proven).
//   PSUM=0: grid 3072. bx<1024 route; else per-expert transpose.
// ------------------------------------------------------------------
template <int PSUM>
__global__ __launch_bounds__(256) void fused_pre(const float* __restrict__ x,
                                                 const float* __restrict__ gw,
                                                 const float* __restrict__ gb,
                                                 const float* __restrict__ ew,
                                                 bf16_t* __restrict__ xbf,
                                                 bf16_t* __restrict__ w2,
                                                 int* __restrict__ cnt,
                                                 int* __restrict__ list) {
    __shared__ __align__(16) char sh[32768];   // route 32KB | transpose 16.6KB
    int bx  = blockIdx.x;
    int tid = threadIdx.x;
    bool is_route;
    int rb, bz;
    if (PSUM) {
        is_route = ((bx & 7) == 0);
        rb = bx >> 3;                        // 0..1023
        bz = bx - (bx >> 3) - 1;             // 0..7167 for non-route blocks
    } else {
        is_route = (bx < 1024);
        rb = bx;
        bz = bx - 1024;                      // 0..2047
    }
    if (is_route) {
        // ---------------- route: 8 tokens/block (R9-proven) ----------------
        float4 gb0 = *(const float4*)gb;
        float4 gb1 = *(const float4*)(gb + 4);
        float gbl[8] = {gb0.x, gb0.y, gb0.z, gb0.w, gb1.x, gb1.y, gb1.z, gb1.w};
        float* gwt = (float*)sh;
        const float4* gw4 = (const float4*)gw;        // gw is [D][8] fp32
        #pragma unroll
        for (int i = 0; i < 8; i++) {
            int f4 = tid + i * 256;
            float4 v = gw4[f4];
            int d  = f4 >> 1;
            int e0 = (f4 & 1) * 4;
            gwt[(e0 + 0) * DIM + d] = v.x;
            gwt[(e0 + 1) * DIM + d] = v.y;
            gwt[(e0 + 2) * DIM + d] = v.z;
            gwt[(e0 + 3) * DIM + d] = v.w;
        }
        __syncthreads();
        int wid  = tid >> 6;
        int lane = tid & 63;
        const float4* gwt4 = (const float4*)gwt;
        for (int tt = 0; tt < 2; tt++) {
            int t = rb * 8 + wid * 2 + tt;
            const float4* xr4 = (const float4*)(x + (size_t)t * DIM);
            float acc[NEXP] = {};
            #pragma unroll
            for (int j = 0; j < 4; j++) {
                int c4 = j * 64 + lane;               // float4 index in row
                float4 v = xr4[c4];
                bf16x4 b;
                b[0] = (bf16_t)v.x; b[1] = (bf16_t)v.y;
                b[2] = (bf16_t)v.z; b[3] = (bf16_t)v.w;
                *(bf16x4*)(xbf + (size_t)t * DIM + c4 * 4) = b;
                #pragma unroll
                for (int e = 0; e < NEXP; e++) {
                    float4 g = gwt4[e * 256 + c4];    // conflict-free
                    acc[e] += v.x * g.x + v.y * g.y + v.z * g.z + v.w * g.w;
                }
            }
            for (int off = 32; off >= 1; off >>= 1)
                #pragma unroll
                for (int e = 0; e < NEXP; e++)
                    acc[e] += __shfl_xor(acc[e], off, 64);
            if (lane == 0) {
                float logit[NEXP];
                #pragma unroll
                for (int e = 0; e < NEXP; e++) logit[e] = acc[e] + gbl[e];
                int b1 = 0; float best = logit[0];
                for (int e = 1; e < NEXP; e++) if (logit[e] > best) { best = logit[e]; b1 = e; }
                int b2 = -1; float best2 = -3.0e38f;
                for (int e = 0; e < NEXP; e++) {
                    if (e == b1) continue;
                    if (logit[e] > best2) { best2 = logit[e]; b2 = e; }
                }
                int a = min(b1, b2), bb = max(b1, b2);
                int p = a * 8 + bb;
                int pos = atomicAdd(&cnt[CIDX(p)], 1);   // line-padded counter
                list[p * T_TOK + pos] = t;
            }
        }
    } else {
        // ---- R6-style pair-summed transpose (direct from ew, dual read) ----
        int g   = bz >> 8;                 // pk (PSUM) or expert e
        int rem = bz & 255;
        int f0  = (rem & 15) * 64;
        int d0  = (rem >> 4) * 64;
        float (*tile)[65] = (float (*)[65])sh;
        int a = PSUM ? d_PA[g] : g;
        int b = PSUM ? d_PB[g] : g;
        const float* s1 = ew + ((size_t)a * DIM + d0) * DIM + f0;
        const float* s2 = ew + ((size_t)b * DIM + d0) * DIM + f0;
        int fl = (tid & 15) * 4;
        int dl = tid >> 4;
        #pragma unroll
        for (int i = 0; i < 4; i++) {
            int d = dl + i * 16;
            float4 u = *(const float4*)(s1 + (size_t)d * DIM + fl);
            if (PSUM) {
                float4 v = *(const float4*)(s2 + (size_t)d * DIM + fl);
                u.x += v.x; u.y += v.y; u.z += v.z; u.w += v.w;
            }
            tile[d][fl + 0] = u.x; tile[d][fl + 1] = u.y;
            tile[d][fl + 2] = u.z; tile[d][fl + 3] = u.w;
        }
        __syncthreads();
        bf16_t* dst = w2 + ((size_t)g * DIM + f0) * DIM + d0;
        int dl2 = (tid & 7) * 8;
        int fl2 = tid >> 3;
        #pragma unroll
        for (int i = 0; i < 2; i++) {
            int f = fl2 + i * 32;
            bf16x8 o;
            #pragma unroll
            for (int c = 0; c < 8; c++) o[c] = (bf16_t)tile[dl2 + c][f];
            *(bf16x8*)(dst + (size_t)f * DIM + dl2) = o;
        }
    }
}

// ------------------------------------------------------------------
// grouped GEMM (unchanged from R9): 128x128/item, BK=32, 4 waves,
// double-buffered counted-vmcnt pipeline, bijective XCD partition.
// ------------------------------------------------------------------
template <int PSUM>
__global__ __launch_bounds__(256, 4) void moe_gemm(const bf16_t* __restrict__ xbf,
                                                   const bf16_t* __restrict__ wsrc,
                                                   const int* __restrict__ cnt,
                                                   const int* __restrict__ list,
                                                   float* __restrict__ out) {
    __shared__ __align__(16) bf16_t As[2][BM * BK2];
    __shared__ __align__(16) bf16_t Bs[2][BN * BK2];
    __shared__ int toks[BM];
    __shared__ int s_desc[128];
    __shared__ int s_ntile;
    int tid  = threadIdx.x;
    int lane = tid & 63;
    int wv   = tid >> 6;
    int wm   = wv >> 1, wn = wv & 1;

    if (tid < 64) {
        int c  = cnt[CIDX(tid)];
        int tp = (c + BM - 1) >> 7;
        int pre = 0, tot = 0;
        for (int i = 0; i < 64; i++) {
            int v = __shfl(tp, i, 64);
            if (i < tid) pre += v;
            tot += v;
        }
        for (int j = 0; j < tp; j++)
            s_desc[pre + j] = tid | ((j * BM) << 8);
        if (tid == 0) s_ntile = tot;
    }
    __syncthreads();
    int nwork = s_ntile * (DIM / BN);
    // bijective XCD-balanced mapping (runtime nwork)
    int q = nwork >> 3, r = nwork & 7;
    int xcd  = blockIdx.x & 7;
    int slot = blockIdx.x >> 3;
    int share = q + (xcd < r ? 1 : 0);
    if (slot >= share) return;
    int w = xcd * q + min(xcd, r) + slot;

    int dsc = s_desc[w >> 3];
    int n0  = (w & 7) * BN;
    int p   = dsc & 63;
    int m0  = dsc >> 8;
    int e1  = p >> 3, e2 = p & 7;
    int cp  = cnt[CIDX(p)];
    int valid = min(BM, cp - m0);
    if (tid < BM) toks[tid] = list[p * T_TOK + m0 + min(tid, valid - 1)];
    __syncthreads();

    const bf16_t* asrc[2];
    #pragma unroll
    for (int i = 0; i < 2; i++) {
        int c = i * 256 + tid;
        int rr = c >> 2, js = (c & 3) ^ ((rr >> 1) & 3);
        asrc[i] = xbf + (size_t)toks[rr] * DIM + js * 8;
    }

    f32x4 acc[4][4] = {};
    int lr = lane & 15;
    int lk = (lane >> 4) * 8;

    if (PSUM) {
        const bf16_t* bsrc[2];
        int pk = e1 * 7 - (e1 * (e1 - 1)) / 2 + (e2 - e1 - 1);
        const bf16_t* bb = wsrc + (size_t)pk * DIM * DIM;
        #pragma unroll
        for (int i = 0; i < 2; i++) {
            int c = i * 256 + tid;
            int rr = c >> 2, js = (c & 3) ^ ((rr >> 1) & 3);
            bsrc[i] = bb + (size_t)(n0 + rr) * DIM + js * 8;
        }
        #pragma unroll
        for (int i = 0; i < 2; i++)
            gload16(asrc[i], &As[0][(i * 256 + wv * 64) * 8]);
        #pragma unroll
        for (int i = 0; i < 2; i++)
            gload16(bsrc[i], &Bs[0][(i * 256 + wv * 64) * 8]);

        for (int ks = 0; ks < DIM / BK2; ks++) {
            int cur = ks & 1;
            if (ks < DIM / BK2 - 1) {
                int k1 = (ks + 1) * BK2;
                #pragma unroll
                for (int i = 0; i < 2; i++)
                    gload16(asrc[i] + k1, &As[cur ^ 1][(i * 256 + wv * 64) * 8]);
                #pragma unroll
                for (int i = 0; i < 2; i++)
                    gload16(bsrc[i] + k1, &Bs[cur ^ 1][(i * 256 + wv * 64) * 8]);
                WAITCNT_VM4();      // wait only tile-ks loads
            } else {
                WAITCNT_VM0();      // last tile: drain
            }
            BARRIER();
            const char* Ab = (const char*)As[cur];
            const char* Bb = (const char*)Bs[cur];
            bf16x8 af[4], bfr[4];
            #pragma unroll
            for (int mf = 0; mf < 4; mf++)
                af[mf] = *(const bf16x8*)(Ab + swz32(wm * 64 + mf * 16 + lr, lk));
            #pragma unroll
            for (int nf = 0; nf < 4; nf++)
                bfr[nf] = *(const bf16x8*)(Bb + swz32(wn * 64 + nf * 16 + lr, lk));
            #pragma unroll
            for (int mf = 0; mf < 4; mf++)
                #pragma unroll
                for (int nf = 0; nf < 4; nf++)
                    acc[mf][nf] = __builtin_amdgcn_mfma_f32_16x16x32_bf16(
                        af[mf], bfr[nf], acc[mf][nf], 0, 0, 0);
            BARRIER();
        }
    } else {
        const bf16_t* wt1 = wsrc + (size_t)e1 * DIM * DIM;
        const bf16_t* wt2 = wsrc + (size_t)e2 * DIM * DIM;
        for (int ks = 0; ks < DIM / BK2; ks++) {
            int k0 = ks * BK2;
            #pragma unroll
            for (int i = 0; i < 2; i++)
                gload16(asrc[i] + k0, &As[0][(i * 256 + wv * 64) * 8]);
            #pragma unroll
            for (int i = 0; i < 2; i++) {
                int c = i * 256 + tid;
                int f = c >> 2, j = c & 3;
                const bf16_t* s1 = wt1 + (size_t)(n0 + f) * DIM + k0 + j * 8;
                const bf16_t* s2 = wt2 + (size_t)(n0 + f) * DIM + k0 + j * 8;
                bf16x8 u = *(const bf16x8*)s1, w2v = *(const bf16x8*)s2, o;
                #pragma unroll
                for (int t = 0; t < 8; t++) o[t] = (bf16_t)((float)u[t] + (float)w2v[t]);
                *(bf16x8*)((char*)Bs[0] + swz32(f, j * 8)) = o;
            }
            WAITCNT_LGKM0();
            WAITCNT_VM0();
            BARRIER();
            const char* Ab = (const char*)As[0];
            const char* Bb = (const char*)Bs[0];
            bf16x8 af[4], bfr[4];
            #pragma unroll
            for (int mf = 0; mf < 4; mf++)
                af[mf] = *(const bf16x8*)(Ab + swz32(wm * 64 + mf * 16 + lr, lk));
            #pragma unroll
            for (int nf = 0; nf < 4; nf++)
                bfr[nf] = *(const bf16x8*)(Bb + swz32(wn * 64 + nf * 16 + lr, lk));
            #pragma unroll
            for (int mf = 0; mf < 4; mf++)
                #pragma unroll
                for (int nf = 0; nf < 4; nf++)
                    acc[mf][nf] = __builtin_amdgcn_mfma_f32_16x16x32_bf16(
                        af[mf], bfr[nf], acc[mf][nf], 0, 0, 0);
            BARRIER();
        }
    }

    #pragma unroll
    for (int mf = 0; mf < 4; mf++) {
        #pragma unroll
        for (int reg = 0; reg < 4; reg++) {
            int rl = wm * 64 + mf * 16 + (lane >> 4) * 4 + reg;
            if (rl < valid) {
                size_t trow = (size_t)toks[rl] * DIM;
                #pragma unroll
                for (int nf = 0; nf < 4; nf++)
                    out[trow + n0 + wn * 64 + nf * 16 + lr] = acc[mf][nf][reg];
            }
        }
    }
}

// ------------------------------------------------------------------
extern "C" void kernel_launch(void* const* d_in, const int* in_sizes, int n_in,
                              void* d_out, int out_size, void* d_ws, size_t ws_size,
                              hipStream_t stream) {
    const float* x  = (const float*)d_in[0];
    const float* gw = (const float*)d_in[1];
    const float* gb = (const float*)d_in[2];
    const float* ew = (const float*)d_in[3];
    float* out = (float*)d_out;
    char* ws = (char*)d_ws;
    int*    cnt  = (int*)(ws + WS_CNT);
    int*    list = (int*)(ws + WS_LIST);
    bf16_t* xbf  = (bf16_t*)(ws + WS_XBF);
    bf16_t* w2   = (bf16_t*)(ws + WS_W2);
    bool psum = (ws_size >= WS_NEED_PSUM);

    zero_cnt<<<dim3(1), 256, 0, stream>>>((int4*)cnt);
    if (psum) {
        fused_pre<1><<<dim3(8192), 256, 0, stream>>>(x, gw, gb, ew,
                                                     xbf, w2, cnt, list);
        moe_gemm<1><<<dim3(1024), 256, 0, stream>>>(xbf, w2, cnt, list, out);
    } else {
        fused_pre<0><<<dim3(1024 + 8 * 256), 256, 0, stream>>>(x, gw, gb, ew,
                                                               xbf, w2, cnt, list);
        moe_gemm<0><<<dim3(1024), 256, 0, stream>>>(xbf, w2, cnt, list, out);
    }
}

// Round 13
// 71.769 us; speedup vs baseline: 1.5698x; 1.5698x over previous
//
#include <hip/hip_runtime.h>
#include <hip/hip_bf16.h>
#include <stdint.h>

#define T_TOK 8192
#define DIM   1024
#define NEXP  8
#define BM    128
#define BN    128
#define BK2   32

typedef __bf16 bf16_t;
typedef bf16_t bf16x8 __attribute__((ext_vector_type(8)));
typedef bf16_t bf16x4 __attribute__((ext_vector_type(4)));
typedef float  f32x4  __attribute__((ext_vector_type(4)));

// ---- workspace layout (bytes) ----
// cnt: 64 counters, EACH ON ITS OWN 64B CACHE LINE (atomic ping-pong fix, R6)
#define WS_CNT    0                  // 64 * 16 ints = 4 KB
#define CIDX(p)   ((p) << 4)
#define WS_LIST   8192               // 64 * 8192 ints = 2 MB
#define WS_XBF    (4u << 20)         // T*D bf16 = 16 MB
#define WS_W2     (20u << 20)        // WSUM 28*2MB = 56 MB (psum) or WT 16MB (fallback)
#define WS_NEED_PSUM ((size_t)76 << 20)
// WT (16 MB bf16) lives in d_out during pre-phase (psum path): dead before GEMM,
// and GEMM rewrites every output element exactly once (R5-proven).

// pair index tables: pk -> (a,b), a<b
__device__ const int d_PA[28] = {0,0,0,0,0,0,0,1,1,1,1,1,1,2,2,2,2,2,3,3,3,3,4,4,4,5,5,6};
__device__ const int d_PB[28] = {1,2,3,4,5,6,7,2,3,4,5,6,7,3,4,5,6,7,4,5,6,7,5,6,7,6,7,7};

// async 16B global -> LDS (lds dest is wave-uniform base; HW adds lane*16)
__device__ __forceinline__ void gload16(const void* g, void* l) {
    __builtin_amdgcn_global_load_lds(
        (const __attribute__((address_space(1))) unsigned int*)g,
        (__attribute__((address_space(3))) unsigned int*)l, 16, 0, 0);
}

// BK2=32 tile: row = 64B = 4 chunks of 16B; chunk' = chunk ^ ((r>>1)&3)
// -> max 2-way bank aliasing on ds_read_b128 (free). k in elements.
__device__ __forceinline__ int swz32(int r, int k) {
    return ((r * BK2 + k) * 2) ^ (((r >> 1) & 3) << 4);
}

#define WAITCNT_VM0()   do { asm volatile("s_waitcnt vmcnt(0)" ::: "memory"); \
                             __builtin_amdgcn_sched_barrier(0); } while (0)
#define WAITCNT_VM4()   do { asm volatile("s_waitcnt vmcnt(4)" ::: "memory"); \
                             __builtin_amdgcn_sched_barrier(0); } while (0)
#define WAITCNT_LGKM0() do { asm volatile("s_waitcnt lgkmcnt(0)" ::: "memory"); \
                             __builtin_amdgcn_sched_barrier(0); } while (0)
#define BARRIER()       do { __builtin_amdgcn_s_barrier(); \
                             __builtin_amdgcn_sched_barrier(0); } while (0)

// ------------------------------------------------------------------
// zero_cnt: zero the 4 KB counter region
// ------------------------------------------------------------------
__global__ void zero_cnt(int4* cnt4) {
    cnt4[threadIdx.x] = int4{0, 0, 0, 0};   // 256 * 16 B = 4 KB
}

// ------------------------------------------------------------------
// pre1: blocks [0,1024) = route (R9-exact, 8 tokens each);
//       blocks [1024,3072) = single-expert transpose WT[e][f][d]=bf16(ew[e][d][f]).
// Sequential ranges (NOT interleaved - R12 lesson). Independent inputs overlap
// naturally as route blocks retire.
// ------------------------------------------------------------------
__global__ __launch_bounds__(256) void pre1(const float* __restrict__ x,
                                            const float* __restrict__ gw,
                                            const float* __restrict__ gb,
                                            const float* __restrict__ ew,
                                            bf16_t* __restrict__ xbf,
                                            bf16_t* __restrict__ wt,
                                            int* __restrict__ cnt,
                                            int* __restrict__ list) {
    __shared__ __align__(16) float sh[NEXP * DIM];   // 32 KB
    int bx  = blockIdx.x;
    int tid = threadIdx.x;
    if (bx < 1024) {
        // ---------------- route: 8 tokens/block (R9-proven) ----------------
        float4 gb0 = *(const float4*)gb;
        float4 gb1 = *(const float4*)(gb + 4);
        float gbl[8] = {gb0.x, gb0.y, gb0.z, gb0.w, gb1.x, gb1.y, gb1.z, gb1.w};
        float* gwt = sh;
        const float4* gw4 = (const float4*)gw;        // gw is [D][8] fp32
        #pragma unroll
        for (int i = 0; i < 8; i++) {
            int f4 = tid + i * 256;
            float4 v = gw4[f4];
            int d  = f4 >> 1;
            int e0 = (f4 & 1) * 4;
            gwt[(e0 + 0) * DIM + d] = v.x;
            gwt[(e0 + 1) * DIM + d] = v.y;
            gwt[(e0 + 2) * DIM + d] = v.z;
            gwt[(e0 + 3) * DIM + d] = v.w;
        }
        __syncthreads();
        int wid  = tid >> 6;
        int lane = tid & 63;
        const float4* gwt4 = (const float4*)gwt;
        for (int tt = 0; tt < 2; tt++) {
            int t = bx * 8 + wid * 2 + tt;
            const float4* xr4 = (const float4*)(x + (size_t)t * DIM);
            float acc[NEXP] = {};
            #pragma unroll
            for (int j = 0; j < 4; j++) {
                int c4 = j * 64 + lane;               // float4 index in row
                float4 v = xr4[c4];
                bf16x4 b;
                b[0] = (bf16_t)v.x; b[1] = (bf16_t)v.y;
                b[2] = (bf16_t)v.z; b[3] = (bf16_t)v.w;
                *(bf16x4*)(xbf + (size_t)t * DIM + c4 * 4) = b;
                #pragma unroll
                for (int e = 0; e < NEXP; e++) {
                    float4 g = gwt4[e * 256 + c4];    // conflict-free
                    acc[e] += v.x * g.x + v.y * g.y + v.z * g.z + v.w * g.w;
                }
            }
            for (int off = 32; off >= 1; off >>= 1)
                #pragma unroll
                for (int e = 0; e < NEXP; e++)
                    acc[e] += __shfl_xor(acc[e], off, 64);
            if (lane == 0) {
                float logit[NEXP];
                #pragma unroll
                for (int e = 0; e < NEXP; e++) logit[e] = acc[e] + gbl[e];
                int b1 = 0; float best = logit[0];
                for (int e = 1; e < NEXP; e++) if (logit[e] > best) { best = logit[e]; b1 = e; }
                int b2 = -1; float best2 = -3.0e38f;
                for (int e = 0; e < NEXP; e++) {
                    if (e == b1) continue;
                    if (logit[e] > best2) { best2 = logit[e]; b2 = e; }
                }
                int a = min(b1, b2), bb = max(b1, b2);
                int p = a * 8 + bb;
                int pos = atomicAdd(&cnt[CIDX(p)], 1);   // line-padded counter
                list[p * T_TOK + pos] = t;
            }
        }
    } else {
        // ---- single-expert transpose: WT[e][f][d] = bf16(ew[e][d][f]) ----
        int bz  = bx - 1024;               // 0..2047
        int g   = bz >> 8;                 // expert e
        int rem = bz & 255;
        int f0  = (rem & 15) * 64;
        int d0  = (rem >> 4) * 64;
        float (*tile)[65] = (float (*)[65])sh;
        const float* s1 = ew + ((size_t)g * DIM + d0) * DIM + f0;
        int fl = (tid & 15) * 4;
        int dl = tid >> 4;
        #pragma unroll
        for (int i = 0; i < 4; i++) {
            int d = dl + i * 16;
            float4 u = *(const float4*)(s1 + (size_t)d * DIM + fl);
            tile[d][fl + 0] = u.x; tile[d][fl + 1] = u.y;
            tile[d][fl + 2] = u.z; tile[d][fl + 3] = u.w;
        }
        __syncthreads();
        bf16_t* dst = wt + ((size_t)g * DIM + f0) * DIM + d0;
        int dl2 = (tid & 7) * 8;
        int fl2 = tid >> 3;
        #pragma unroll
        for (int i = 0; i < 2; i++) {
            int f = fl2 + i * 32;
            bf16x8 o;
            #pragma unroll
            for (int c = 0; c < 8; c++) o[c] = (bf16_t)tile[dl2 + c][f];
            *(bf16x8*)(dst + (size_t)f * DIM + dl2) = o;
        }
    }
}

// ------------------------------------------------------------------
// pairsum: WSUM[pk] = WT[a] + WT[b]; pure coalesced bf16x8 streaming
// (R5-proven code; the 64 us it showed then was the counter atomic bug).
// 3584 blocks x 256 thr; 16 KB out per block.
// ------------------------------------------------------------------
__global__ __launch_bounds__(256) void pairsum(const bf16_t* __restrict__ wt,
                                               bf16_t* __restrict__ wsum) {
    int bz = blockIdx.x;           // 0..3583
    int pk = bz >> 7;              // /128
    int cx = bz & 127;
    int tid = threadIdx.x;
    const bf16x8* wa = (const bf16x8*)(wt + (size_t)d_PA[pk] * DIM * DIM);
    const bf16x8* wb = (const bf16x8*)(wt + (size_t)d_PB[pk] * DIM * DIM);
    bf16x8*       wo = (bf16x8*)(wsum + (size_t)pk * DIM * DIM);
    int base = cx * 1024 + tid;
    #pragma unroll
    for (int it = 0; it < 4; it++) {
        int c = base + it * 256;
        bf16x8 u = wa[c], v = wb[c], o;
        #pragma unroll
        for (int i = 0; i < 8; i++) o[i] = (bf16_t)((float)u[i] + (float)v[i]);
        wo[c] = o;
    }
}

// ------------------------------------------------------------------
// grouped GEMM (unchanged from R9/R11): 128x128/item, BK=32, 4 waves,
// double-buffered counted-vmcnt pipeline, bijective XCD partition.
// ------------------------------------------------------------------
template <int PSUM>
__global__ __launch_bounds__(256, 4) void moe_gemm(const bf16_t* __restrict__ xbf,
                                                   const bf16_t* __restrict__ wsrc,
                                                   const int* __restrict__ cnt,
                                                   const int* __restrict__ list,
                                                   float* __restrict__ out) {
    __shared__ __align__(16) bf16_t As[2][BM * BK2];
    __shared__ __align__(16) bf16_t Bs[2][BN * BK2];
    __shared__ int toks[BM];
    __shared__ int s_desc[128];
    __shared__ int s_ntile;
    int tid  = threadIdx.x;
    int lane = tid & 63;
    int wv   = tid >> 6;
    int wm   = wv >> 1, wn = wv & 1;

    if (tid < 64) {
        int c  = cnt[CIDX(tid)];
        int tp = (c + BM - 1) >> 7;
        int pre = 0, tot = 0;
        for (int i = 0; i < 64; i++) {
            int v = __shfl(tp, i, 64);
            if (i < tid) pre += v;
            tot += v;
        }
        for (int j = 0; j < tp; j++)
            s_desc[pre + j] = tid | ((j * BM) << 8);
        if (tid == 0) s_ntile = tot;
    }
    __syncthreads();
    int nwork = s_ntile * (DIM / BN);
    // bijective XCD-balanced mapping (runtime nwork)
    int q = nwork >> 3, r = nwork & 7;
    int xcd  = blockIdx.x & 7;
    int slot = blockIdx.x >> 3;
    int share = q + (xcd < r ? 1 : 0);
    if (slot >= share) return;
    int w = xcd * q + min(xcd, r) + slot;

    int dsc = s_desc[w >> 3];
    int n0  = (w & 7) * BN;
    int p   = dsc & 63;
    int m0  = dsc >> 8;
    int e1  = p >> 3, e2 = p & 7;
    int cp  = cnt[CIDX(p)];
    int valid = min(BM, cp - m0);
    if (tid < BM) toks[tid] = list[p * T_TOK + m0 + min(tid, valid - 1)];
    __syncthreads();

    const bf16_t* asrc[2];
    #pragma unroll
    for (int i = 0; i < 2; i++) {
        int c = i * 256 + tid;
        int rr = c >> 2, js = (c & 3) ^ ((rr >> 1) & 3);
        asrc[i] = xbf + (size_t)toks[rr] * DIM + js * 8;
    }

    f32x4 acc[4][4] = {};
    int lr = lane & 15;
    int lk = (lane >> 4) * 8;

    if (PSUM) {
        const bf16_t* bsrc[2];
        int pk = e1 * 7 - (e1 * (e1 - 1)) / 2 + (e2 - e1 - 1);
        const bf16_t* bb = wsrc + (size_t)pk * DIM * DIM;
        #pragma unroll
        for (int i = 0; i < 2; i++) {
            int c = i * 256 + tid;
            int rr = c >> 2, js = (c & 3) ^ ((rr >> 1) & 3);
            bsrc[i] = bb + (size_t)(n0 + rr) * DIM + js * 8;
        }
        #pragma unroll
        for (int i = 0; i < 2; i++)
            gload16(asrc[i], &As[0][(i * 256 + wv * 64) * 8]);
        #pragma unroll
        for (int i = 0; i < 2; i++)
            gload16(bsrc[i], &Bs[0][(i * 256 + wv * 64) * 8]);

        for (int ks = 0; ks < DIM / BK2; ks++) {
            int cur = ks & 1;
            if (ks < DIM / BK2 - 1) {
                int k1 = (ks + 1) * BK2;
                #pragma unroll
                for (int i = 0; i < 2; i++)
                    gload16(asrc[i] + k1, &As[cur ^ 1][(i * 256 + wv * 64) * 8]);
                #pragma unroll
                for (int i = 0; i < 2; i++)
                    gload16(bsrc[i] + k1, &Bs[cur ^ 1][(i * 256 + wv * 64) * 8]);
                WAITCNT_VM4();      // wait only tile-ks loads
            } else {
                WAITCNT_VM0();      // last tile: drain
            }
            BARRIER();
            const char* Ab = (const char*)As[cur];
            const char* Bb = (const char*)Bs[cur];
            bf16x8 af[4], bfr[4];
            #pragma unroll
            for (int mf = 0; mf < 4; mf++)
                af[mf] = *(const bf16x8*)(Ab + swz32(wm * 64 + mf * 16 + lr, lk));
            #pragma unroll
            for (int nf = 0; nf < 4; nf++)
                bfr[nf] = *(const bf16x8*)(Bb + swz32(wn * 64 + nf * 16 + lr, lk));
            #pragma unroll
            for (int mf = 0; mf < 4; mf++)
                #pragma unroll
                for (int nf = 0; nf < 4; nf++)
                    acc[mf][nf] = __builtin_amdgcn_mfma_f32_16x16x32_bf16(
                        af[mf], bfr[nf], acc[mf][nf], 0, 0, 0);
            BARRIER();
        }
    } else {
        const bf16_t* wt1 = wsrc + (size_t)e1 * DIM * DIM;
        const bf16_t* wt2 = wsrc + (size_t)e2 * DIM * DIM;
        for (int ks = 0; ks < DIM / BK2; ks++) {
            int k0 = ks * BK2;
            #pragma unroll
            for (int i = 0; i < 2; i++)
                gload16(asrc[i] + k0, &As[0][(i * 256 + wv * 64) * 8]);
            #pragma unroll
            for (int i = 0; i < 2; i++) {
                int c = i * 256 + tid;
                int f = c >> 2, j = c & 3;
                const bf16_t* s1 = wt1 + (size_t)(n0 + f) * DIM + k0 + j * 8;
                const bf16_t* s2 = wt2 + (size_t)(n0 + f) * DIM + k0 + j * 8;
                bf16x8 u = *(const bf16x8*)s1, w2v = *(const bf16x8*)s2, o;
                #pragma unroll
                for (int t = 0; t < 8; t++) o[t] = (bf16_t)((float)u[t] + (float)w2v[t]);
                *(bf16x8*)((char*)Bs[0] + swz32(f, j * 8)) = o;
            }
            WAITCNT_LGKM0();
            WAITCNT_VM0();
            BARRIER();
            const char* Ab = (const char*)As[0];
            const char* Bb = (const char*)Bs[0];
            bf16x8 af[4], bfr[4];
            #pragma unroll
            for (int mf = 0; mf < 4; mf++)
                af[mf] = *(const bf16x8*)(Ab + swz32(wm * 64 + mf * 16 + lr, lk));
            #pragma unroll
            for (int nf = 0; nf < 4; nf++)
                bfr[nf] = *(const bf16x8*)(Bb + swz32(wn * 64 + nf * 16 + lr, lk));
            #pragma unroll
            for (int mf = 0; mf < 4; mf++)
                #pragma unroll
                for (int nf = 0; nf < 4; nf++)
                    acc[mf][nf] = __builtin_amdgcn_mfma_f32_16x16x32_bf16(
                        af[mf], bfr[nf], acc[mf][nf], 0, 0, 0);
            BARRIER();
        }
    }

    #pragma unroll
    for (int mf = 0; mf < 4; mf++) {
        #pragma unroll
        for (int reg = 0; reg < 4; reg++) {
            int rl = wm * 64 + mf * 16 + (lane >> 4) * 4 + reg;
            if (rl < valid) {
                size_t trow = (size_t)toks[rl] * DIM;
                #pragma unroll
                for (int nf = 0; nf < 4; nf++)
                    out[trow + n0 + wn * 64 + nf * 16 + lr] = acc[mf][nf][reg];
            }
        }
    }
}

// ------------------------------------------------------------------
extern "C" void kernel_launch(void* const* d_in, const int* in_sizes, int n_in,
                              void* d_out, int out_size, void* d_ws, size_t ws_size,
                              hipStream_t stream) {
    const float* x  = (const float*)d_in[0];
    const float* gw = (const float*)d_in[1];
    const float* gb = (const float*)d_in[2];
    const float* ew = (const float*)d_in[3];
    float* out = (float*)d_out;
    char* ws = (char*)d_ws;
    int*    cnt  = (int*)(ws + WS_CNT);
    int*    list = (int*)(ws + WS_LIST);
    bf16_t* xbf  = (bf16_t*)(ws + WS_XBF);
    bf16_t* w2   = (bf16_t*)(ws + WS_W2);
    bool psum = (ws_size >= WS_NEED_PSUM);

    zero_cnt<<<dim3(1), 256, 0, stream>>>((int4*)cnt);
    if (psum) {
        bf16_t* wt_tmp = (bf16_t*)d_out;   // WT scratch in d_out (R5-proven)
        pre1<<<dim3(3072), 256, 0, stream>>>(x, gw, gb, ew, xbf, wt_tmp, cnt, list);
        pairsum<<<dim3(3584), 256, 0, stream>>>(wt_tmp, w2);
        moe_gemm<1><<<dim3(1024), 256, 0, stream>>>(xbf, w2, cnt, list, out);
    } else {
        pre1<<<dim3(3072), 256, 0, stream>>>(x, gw, gb, ew, xbf, w2, cnt, list);
        moe_gemm<0><<<dim3(1024), 256, 0, stream>>>(xbf, w2, cnt, list, out);
    }
}